// Round 1
// baseline (203.954 us; speedup 1.0000x reference)
//
#include <hip/hip_runtime.h>
#include <hip/hip_bf16.h>
#include <stdint.h>

#define Bn 4
#define Cn 64
#define Fn 50000
#define Kn 16
#define NTOT (Bn*Fn)
#define EPS 1e-5f

typedef unsigned short u16;
typedef unsigned int u32;
typedef __attribute__((ext_vector_type(8))) short short8;
typedef __attribute__((ext_vector_type(4))) float f32x4;
typedef __attribute__((ext_vector_type(4))) int i32x4;
typedef __attribute__((ext_vector_type(4))) unsigned int u32x4;

__device__ __forceinline__ u16 f2bf(float x) {
  __hip_bfloat16 h = __float2bfloat16(x);
  return *reinterpret_cast<u16*>(&h);
}
__device__ __forceinline__ u32 pack2(float a, float b) {
  return (u32)f2bf(a) | ((u32)f2bf(b) << 16);
}

// K1 (MFMA): Gt[b][face][64ch] bf16 (128 B rows) = W x fea[b].
// 128-f tile. fea staged via wide coalesced float4 loads into LDS [c][f] fp32
// (row stride 129 dwords -> frag reads are <=2-way bank aliased = free);
// B-frags built from 16 ds_read_b32. MFMA layouts (m89-verified):
//   A[m=lane&15][k=quad*8+j], B[k=quad*8+j][n=lane&15], D: row=quad*4+r, col=lane&15.
// Epilogue: LDS transpose (reuse a_s) -> contiguous 128B-per-face row writes.
__global__ __launch_bounds__(256) void k1_mfma(
    const float* __restrict__ fea, const float* __restrict__ W,
    u32* __restrict__ Gt) {
  const int b = blockIdx.y;
  const int f0 = blockIdx.x * 128;
  const int t = threadIdx.x;
  const int l = t & 63;
  const int quad = l >> 4;
  const int lane15 = l & 15;
  const int wv = t >> 6;
  __shared__ float a_s[64][129];   // 33 KB -> 4 blocks/CU

  // A-frags: o = ot*16 + lane15, c = kk*32 + quad*8 + j
  short8 afr[4][2];
  #pragma unroll
  for (int ot = 0; ot < 4; ot++) {
    #pragma unroll
    for (int kk = 0; kk < 2; kk++) {
      const float* wr = W + (ot * 16 + lane15) * 64 + kk * 32 + quad * 8;
      float4 wa = *(const float4*)wr;
      float4 wb = *(const float4*)(wr + 4);
      union { short8 v; u32 u[4]; } fr;
      fr.u[0] = pack2(wa.x, wa.y); fr.u[1] = pack2(wa.z, wa.w);
      fr.u[2] = pack2(wb.x, wb.y); fr.u[3] = pack2(wb.z, wb.w);
      afr[ot][kk] = fr.v;
    }
  }

  // Stage: 8 independent float4 loads/thread, each half-wave reads a 512 B run
  {
    const float* fb = fea + (size_t)b * Cn * Fn;
    const int f4 = t & 31;          // float4 slot within 128-f tile
    const int cbase = t >> 5;       // 0..7
    const bool fvalid = (f0 + f4 * 4) < Fn;   // Fn%4==0 -> whole float4 valid
    #pragma unroll
    for (int jj = 0; jj < 8; jj++) {
      int c = cbase + jj * 8;
      float4 v = make_float4(0.f, 0.f, 0.f, 0.f);
      if (fvalid) v = *(const float4*)(fb + (size_t)c * Fn + f0 + f4 * 4);
      *(float4*)&a_s[c][f4 * 4] = v;
    }
  }
  __syncthreads();

  f32x4 acc[4][2];
  #pragma unroll
  for (int ot = 0; ot < 4; ot++)
    #pragma unroll
    for (int ft = 0; ft < 2; ft++) acc[ot][ft] = (f32x4){0.f, 0.f, 0.f, 0.f};

  #pragma unroll
  for (int ft = 0; ft < 2; ft++) {
    const int fl = wv * 32 + ft * 16 + lane15;
    float x[16];
    #pragma unroll
    for (int j = 0; j < 8; j++) x[j] = a_s[quad * 8 + j][fl];
    #pragma unroll
    for (int j = 0; j < 8; j++) x[8 + j] = a_s[32 + quad * 8 + j][fl];
    union { short8 s; u32 u[4]; } b0, b1;
    #pragma unroll
    for (int p = 0; p < 4; p++) {
      b0.u[p] = pack2(x[2 * p], x[2 * p + 1]);
      b1.u[p] = pack2(x[8 + 2 * p], x[8 + 2 * p + 1]);
    }
    #pragma unroll
    for (int ot = 0; ot < 4; ot++) {
      acc[ot][ft] = __builtin_amdgcn_mfma_f32_16x16x32_bf16(afr[ot][0], b0.s, acc[ot][ft], 0, 0, 0);
      acc[ot][ft] = __builtin_amdgcn_mfma_f32_16x16x32_bf16(afr[ot][1], b1.s, acc[ot][ft], 0, 0, 0);
    }
  }

  // Epilogue: transpose through LDS (reuse a_s as u32, row stride 36 -> 16B-aligned,
  // <=4-way banks) then write 128 faces x 128 B fully contiguous.
  __syncthreads();                 // all waves done reading a_s
  u32* ts = (u32*)&a_s[0][0];      // 128 * 36 * 4 B = 18.4 KB, fits in 33 KB
  #pragma unroll
  for (int ot = 0; ot < 4; ot++) {
    #pragma unroll
    for (int ft = 0; ft < 2; ft++) {
      int fl = wv * 32 + ft * 16 + lane15;
      uint2 pv;
      pv.x = pack2(acc[ot][ft][0], acc[ot][ft][1]);
      pv.y = pack2(acc[ot][ft][2], acc[ot][ft][3]);
      *(uint2*)&ts[fl * 36 + ot * 8 + quad * 2] = pv;   // slot j covers ch (2j,2j+1)
    }
  }
  __syncthreads();
  #pragma unroll
  for (int j = 0; j < 4; j++) {
    int o = j * 1024 + t * 4;       // u32 offset in 128x32 tile
    int fl = o >> 5, sl = o & 31;
    if (f0 + fl < Fn) {
      u32x4 vv = *(const u32x4*)&ts[fl * 36 + sl];
      *(u32x4*)(Gt + ((size_t)b * Fn + f0 + fl) * 32 + sl) = vv;
    }
  }
}

// K2: face-major gather. Block = 256 thr: 32 faces x 8 ch-slices (16 B each).
// One neighbor row = one aligned 128 B line, fetched ONCE per (b,face) by the
// 8-thread group (coalesced). Persistent grid: 2048 blocks, b = (bid&7)>>1
// pins each b's 6.4 MB Gt slice to 2 XCDs' L2. Stats accumulate in registers
// across the tile loop; one atomic round per block.
template<int WRITE_BF16>
__global__ __launch_bounds__(256) void k2_gather(
    const u32* __restrict__ Gt, const int* __restrict__ ring,
    const float* __restrict__ bias, u32* __restrict__ Y, float* __restrict__ outF,
    float* __restrict__ gsum, float* __restrict__ gsum2) {
  const int bid = blockIdx.x;
  const int b = (bid & 7) >> 1;                    // XCD bid%8 -> 2 XCDs per b
  const int sub = ((bid >> 3) << 1) | (bid & 1);   // 0..511 within b
  const int t = threadIdx.x;
  const int gid = t >> 3;    // face within 32-face tile
  const int cs = t & 7;      // 16 B channel slice (channels cs*8 .. cs*8+7)
  const int sch = t & 63;    // stats channel
  const int spart = t >> 6;  // stats face-part

  __shared__ float y_s[32][65];
  __shared__ float rs[4][64];
  __shared__ float rs2[4][64];

  float bv[8];
  #pragma unroll
  for (int i = 0; i < 8; i++) bv[i] = bias[cs * 8 + i];

  const u32* Gb = Gt + (size_t)b * Fn * 32;
  const int* rb = ring + (size_t)b * Fn * Kn;

  float sacc = 0.f, s2acc = 0.f;
  const int ntiles = (Fn + 31) / 32;   // 1563

  for (int tile = sub; tile < ntiles; tile += 512) {
    const int fa = tile * 32 + gid;
    const bool valid = fa < Fn;
    float acc[8];
    #pragma unroll
    for (int i = 0; i < 8; i++) acc[i] = 0.f;

    if (valid) {
      const i32x4* rp = (const i32x4*)(rb + (size_t)fa * Kn);
      i32x4 i0 = __builtin_nontemporal_load(&rp[0]);
      i32x4 i1 = __builtin_nontemporal_load(&rp[1]);
      i32x4 i2 = __builtin_nontemporal_load(&rp[2]);
      i32x4 i3 = __builtin_nontemporal_load(&rp[3]);
      int idx[16] = {i0[0],i0[1],i0[2],i0[3], i1[0],i1[1],i1[2],i1[3],
                     i2[0],i2[1],i2[2],i2[3], i3[0],i3[1],i3[2],i3[3]};
      u32x4 v[8];
      #pragma unroll
      for (int k = 0; k < 8; k++)
        v[k] = *(const u32x4*)(Gb + (size_t)idx[k] * 32 + cs * 4);
      #pragma unroll
      for (int k = 0; k < 8; k++) {
        #pragma unroll
        for (int p = 0; p < 4; p++) {
          u32 uu = v[k][p];
          acc[2*p]   += __uint_as_float(uu << 16);
          acc[2*p+1] += __uint_as_float(uu & 0xffff0000u);
        }
      }
      u32x4 w[8];
      #pragma unroll
      for (int k = 0; k < 8; k++)
        w[k] = *(const u32x4*)(Gb + (size_t)idx[8 + k] * 32 + cs * 4);
      #pragma unroll
      for (int k = 0; k < 8; k++) {
        #pragma unroll
        for (int p = 0; p < 4; p++) {
          u32 uu = w[k][p];
          acc[2*p]   += __uint_as_float(uu << 16);
          acc[2*p+1] += __uint_as_float(uu & 0xffff0000u);
        }
      }
    }

    float yv[8];
    #pragma unroll
    for (int i = 0; i < 8; i++) yv[i] = valid ? acc[i] + bv[i] : 0.f;

    if (WRITE_BF16 && valid) {
      u32x4 pv;
      pv[0] = pack2(yv[0], yv[1]); pv[1] = pack2(yv[2], yv[3]);
      pv[2] = pack2(yv[4], yv[5]); pv[3] = pack2(yv[6], yv[7]);
      __builtin_nontemporal_store(pv,
          (u32x4*)(Y + ((size_t)b * Fn + fa) * 32 + cs * 4));
    }

    // stats staging: y_s[face][ch], pad 65 -> conflict-free
    #pragma unroll
    for (int i = 0; i < 8; i++) y_s[gid][cs * 8 + i] = yv[i];
    __syncthreads();
    #pragma unroll
    for (int i = 0; i < 8; i++) {
      float v = y_s[spart * 8 + i][sch];
      sacc += v; s2acc += v * v;
    }
    if (!WRITE_BF16) {
      // fallback: write fp32 y to out[b][ch][f] from staged tile
      const int ch = t >> 2, q = t & 3;
      #pragma unroll
      for (int jj = 0; jj < 2; jj++) {
        int f4 = q + jj * 4;                 // float4 index within tile
        int fb = tile * 32 + f4 * 4;
        if (fb < Fn) {
          float4 wv4;
          wv4.x = y_s[f4 * 4 + 0][ch]; wv4.y = y_s[f4 * 4 + 1][ch];
          wv4.z = y_s[f4 * 4 + 2][ch]; wv4.w = y_s[f4 * 4 + 3][ch];
          *(float4*)(outF + ((size_t)b * 64 + ch) * Fn + fb) = wv4;
        }
      }
    }
    __syncthreads();
  }

  rs[spart][sch] = sacc;
  rs2[spart][sch] = s2acc;
  __syncthreads();
  if (t < 64) {
    float s = rs[0][t] + rs[1][t] + rs[2][t] + rs[3][t];
    atomicAdd(&gsum[t], s);
  } else if (t < 128) {
    const int ch = t - 64;
    float s2 = rs2[0][ch] + rs2[1][ch] + rs2[2][ch] + rs2[3][ch];
    atomicAdd(&gsum2[ch], s2);
  }
}

__global__ void k3_stats(const float* __restrict__ gsum, const float* __restrict__ gsum2,
                         const float* __restrict__ gamma, const float* __restrict__ beta,
                         float* __restrict__ ab) {
  int o = threadIdx.x;
  if (o < 64) {
    float inv = 1.0f / (float)NTOT;
    float mean = gsum[o] * inv;
    float var = gsum2[o] * inv - mean * mean;  // biased
    float r = rsqrtf(var + EPS);
    float a = gamma[o] * r;
    ab[o] = a;
    ab[64 + o] = beta[o] - mean * a;
  }
}

// k4 (bf16, k3 fused): transpose Y[b][face][64ch] bf16 -> out[b][ch][face] fp32
// with BN affine + relu. 64-face x 64-ch tiles via LDS; coalesced both sides.
__global__ __launch_bounds__(256) void k4_norm_bf(
    const u32* __restrict__ Y, const float* __restrict__ gsum,
    const float* __restrict__ gsum2, const float* __restrict__ gamma,
    const float* __restrict__ beta, float* __restrict__ out) {
  const int b = blockIdx.y;
  const int f0 = blockIdx.x * 64;
  const int t = threadIdx.x;
  __shared__ u32 ys[32][65];   // [ch-pair][face], pad 65 -> ~2-way banks

  #pragma unroll
  for (int j = 0; j < 2; j++) {
    int o = j * 1024 + t * 4;        // u32 offset in 64x32 tile
    int fl = o >> 5, sl = o & 31;
    u32x4 vv = (u32x4)(0u);
    if (f0 + fl < Fn)
      vv = *(const u32x4*)(Y + ((size_t)b * Fn + f0 + fl) * 32 + sl);
    ys[sl + 0][fl] = vv[0]; ys[sl + 1][fl] = vv[1];
    ys[sl + 2][fl] = vv[2]; ys[sl + 3][fl] = vv[3];
  }
  __syncthreads();

  const float inv = 1.0f / (float)NTOT;
  const int fi = t & 15, g = t >> 4;
  const int fbase = 4 * fi;
  #pragma unroll
  for (int j = 0; j < 4; j++) {
    int ch = g * 4 + j;
    float mean = gsum[ch] * inv;
    float var = gsum2[ch] * inv - mean * mean;
    float a = gamma[ch] * rsqrtf(var + EPS);
    float cc = beta[ch] - mean * a;
    if (f0 + fbase < Fn) {           // Fn%4==0 -> whole float4 valid
      const int c2 = ch >> 1;
      const bool hi = ch & 1;
      float r[4];
      #pragma unroll
      for (int rr = 0; rr < 4; rr++) {
        u32 u = ys[c2][fbase + rr];
        float xv = __uint_as_float(hi ? (u & 0xffff0000u) : (u << 16));
        r[rr] = fmaxf(fmaf(xv, a, cc), 0.f);
      }
      float4 res = make_float4(r[0], r[1], r[2], r[3]);
      *(float4*)(out + ((size_t)b * 64 + ch) * Fn + f0 + fbase) = res;
    }
  }
}

// k4 (fallback): in-place fp32 normalize
__global__ __launch_bounds__(256) void k4_norm_f32(float* __restrict__ out,
                                                   const float* __restrict__ ab) {
  int i = blockIdx.x * 256 + threadIdx.x;   // float4 index
  int o = (i / (Fn / 4)) & 63;
  float a = ab[o], c = ab[64 + o];
  float4 v = ((float4*)out)[i];
  v.x = fmaxf(fmaf(v.x, a, c), 0.f);
  v.y = fmaxf(fmaf(v.y, a, c), 0.f);
  v.z = fmaxf(fmaf(v.z, a, c), 0.f);
  v.w = fmaxf(fmaf(v.w, a, c), 0.f);
  ((float4*)out)[i] = v;
}

extern "C" void kernel_launch(void* const* d_in, const int* in_sizes, int n_in,
                              void* d_out, int out_size, void* d_ws, size_t ws_size,
                              hipStream_t stream) {
  const float* fea   = (const float*)d_in[0];
  const int*   ring  = (const int*)d_in[1];
  const float* W     = (const float*)d_in[2];
  const float* bias  = (const float*)d_in[3];
  const float* gamma = (const float*)d_in[4];
  const float* beta  = (const float*)d_in[5];
  float* out = (float*)d_out;

  u32* Gt = (u32*)d_ws;                                   // [B][Fn][32 u32] = 25.6 MB
  const size_t gtBytes = (size_t)Bn * Fn * 32 * 4;
  const size_t yBytes  = (size_t)Bn * Fn * 32 * 4;        // [B][Fn][32 u32] = 25.6 MB
  const bool bf16y = ws_size >= gtBytes + yBytes + 1024;

  u32* Y = Gt + (size_t)Bn * Fn * 32;
  float* gsum  = bf16y ? (float*)((char*)d_ws + gtBytes + yBytes)
                       : (float*)((char*)d_ws + gtBytes);
  float* gsum2 = gsum + 64;
  float* ab    = gsum + 128;

  hipMemsetAsync(gsum, 0, 2 * 64 * sizeof(float), stream);
  k1_mfma<<<dim3((Fn + 127) / 128, Bn), 256, 0, stream>>>(fea, W, Gt);
  if (bf16y) {
    k2_gather<1><<<dim3(2048), 256, 0, stream>>>(Gt, ring, bias, Y, out, gsum, gsum2);
    k4_norm_bf<<<dim3((Fn + 63) / 64, Bn), 256, 0, stream>>>(Y, gsum, gsum2, gamma, beta, out);
  } else {
    k2_gather<0><<<dim3(2048), 256, 0, stream>>>(Gt, ring, bias, Y, out, gsum, gsum2);
    k3_stats<<<1, 64, 0, stream>>>(gsum, gsum2, gamma, beta, ab);
    k4_norm_f32<<<dim3((Bn * Cn * Fn / 4) / 256), 256, 0, stream>>>(out, ab);
  }
}

// Round 2
// 202.497 us; speedup vs baseline: 1.0072x; 1.0072x over previous
//
#include <hip/hip_runtime.h>
#include <hip/hip_bf16.h>
#include <stdint.h>

#define Bn 4
#define Cn 64
#define Fn 50000
#define Kn 16
#define NTOT (Bn*Fn)
#define EPS 1e-5f

typedef unsigned short u16;
typedef unsigned int u32;
typedef __attribute__((ext_vector_type(8))) short short8;
typedef __attribute__((ext_vector_type(4))) float f32x4;
typedef __attribute__((ext_vector_type(4))) int i32x4;
typedef __attribute__((ext_vector_type(4))) unsigned int u32x4;

__device__ __forceinline__ u16 f2bf(float x) {
  __hip_bfloat16 h = __float2bfloat16(x);
  return *reinterpret_cast<u16*>(&h);
}
__device__ __forceinline__ u32 pack2(float a, float b) {
  return (u32)f2bf(a) | ((u32)f2bf(b) << 16);
}

// K1 (MFMA): Gt[b][face][64ch] bf16 (128 B rows) = W x fea[b].
// 128-f tile. fea staged via wide coalesced float4 loads into LDS [c][f] fp32
// (row stride 129 dwords -> frag reads are <=2-way bank aliased = free);
// B-frags built from 16 ds_read_b32. MFMA layouts (m89-verified):
//   A[m=lane&15][k=quad*8+j], B[k=quad*8+j][n=lane&15], D: row=quad*4+r, col=lane&15.
// Epilogue: LDS transpose (reuse a_s) -> contiguous 128B-per-face row writes.
__global__ __launch_bounds__(256) void k1_mfma(
    const float* __restrict__ fea, const float* __restrict__ W,
    u32* __restrict__ Gt) {
  const int b = blockIdx.y;
  const int f0 = blockIdx.x * 128;
  const int t = threadIdx.x;
  const int l = t & 63;
  const int quad = l >> 4;
  const int lane15 = l & 15;
  const int wv = t >> 6;
  __shared__ float a_s[64][129];   // 33 KB -> 4 blocks/CU

  // A-frags: o = ot*16 + lane15, c = kk*32 + quad*8 + j
  short8 afr[4][2];
  #pragma unroll
  for (int ot = 0; ot < 4; ot++) {
    #pragma unroll
    for (int kk = 0; kk < 2; kk++) {
      const float* wr = W + (ot * 16 + lane15) * 64 + kk * 32 + quad * 8;
      float4 wa = *(const float4*)wr;
      float4 wb = *(const float4*)(wr + 4);
      union { short8 v; u32 u[4]; } fr;
      fr.u[0] = pack2(wa.x, wa.y); fr.u[1] = pack2(wa.z, wa.w);
      fr.u[2] = pack2(wb.x, wb.y); fr.u[3] = pack2(wb.z, wb.w);
      afr[ot][kk] = fr.v;
    }
  }

  // Stage: 8 independent float4 loads/thread, each half-wave reads a 512 B run
  {
    const float* fb = fea + (size_t)b * Cn * Fn;
    const int f4 = t & 31;          // float4 slot within 128-f tile
    const int cbase = t >> 5;       // 0..7
    const bool fvalid = (f0 + f4 * 4) < Fn;   // Fn%4==0 -> whole float4 valid
    #pragma unroll
    for (int jj = 0; jj < 8; jj++) {
      int c = cbase + jj * 8;
      float4 v = make_float4(0.f, 0.f, 0.f, 0.f);
      if (fvalid) v = *(const float4*)(fb + (size_t)c * Fn + f0 + f4 * 4);
      *(float4*)&a_s[c][f4 * 4] = v;
    }
  }
  __syncthreads();

  f32x4 acc[4][2];
  #pragma unroll
  for (int ot = 0; ot < 4; ot++)
    #pragma unroll
    for (int ft = 0; ft < 2; ft++) acc[ot][ft] = (f32x4){0.f, 0.f, 0.f, 0.f};

  #pragma unroll
  for (int ft = 0; ft < 2; ft++) {
    const int fl = wv * 32 + ft * 16 + lane15;
    float x[16];
    #pragma unroll
    for (int j = 0; j < 8; j++) x[j] = a_s[quad * 8 + j][fl];
    #pragma unroll
    for (int j = 0; j < 8; j++) x[8 + j] = a_s[32 + quad * 8 + j][fl];
    union { short8 s; u32 u[4]; } b0, b1;
    #pragma unroll
    for (int p = 0; p < 4; p++) {
      b0.u[p] = pack2(x[2 * p], x[2 * p + 1]);
      b1.u[p] = pack2(x[8 + 2 * p], x[8 + 2 * p + 1]);
    }
    #pragma unroll
    for (int ot = 0; ot < 4; ot++) {
      acc[ot][ft] = __builtin_amdgcn_mfma_f32_16x16x32_bf16(afr[ot][0], b0.s, acc[ot][ft], 0, 0, 0);
      acc[ot][ft] = __builtin_amdgcn_mfma_f32_16x16x32_bf16(afr[ot][1], b1.s, acc[ot][ft], 0, 0, 0);
    }
  }

  // Epilogue: transpose through LDS (reuse a_s as u32, row stride 36 -> 16B-aligned,
  // <=4-way banks) then write 128 faces x 128 B fully contiguous.
  __syncthreads();                 // all waves done reading a_s
  u32* ts = (u32*)&a_s[0][0];      // 128 * 36 * 4 B = 18.4 KB, fits in 33 KB
  #pragma unroll
  for (int ot = 0; ot < 4; ot++) {
    #pragma unroll
    for (int ft = 0; ft < 2; ft++) {
      int fl = wv * 32 + ft * 16 + lane15;
      uint2 pv;
      pv.x = pack2(acc[ot][ft][0], acc[ot][ft][1]);
      pv.y = pack2(acc[ot][ft][2], acc[ot][ft][3]);
      *(uint2*)&ts[fl * 36 + ot * 8 + quad * 2] = pv;   // slot j covers ch (2j,2j+1)
    }
  }
  __syncthreads();
  #pragma unroll
  for (int j = 0; j < 4; j++) {
    int o = j * 1024 + t * 4;       // u32 offset in 128x32 tile
    int fl = o >> 5, sl = o & 31;
    if (f0 + fl < Fn) {
      u32x4 vv = *(const u32x4*)&ts[fl * 36 + sl];
      *(u32x4*)(Gt + ((size_t)b * Fn + f0 + fl) * 32 + sl) = vv;
    }
  }
}

// K2: face-major gather, BARRIER-FREE main loop. Block = 256 thr: 32 faces x
// 8 ch-slices (16 B each). One neighbor row = one aligned 128 B line, fetched
// once per (b,face) by the 8-thread group. 2048 blocks, b = (bid&7)>>1 pins
// each b's 6.4 MB Gt slice to 2 XCDs. BN stats accumulate in 16 per-thread
// registers across the tile loop (no per-tile LDS/syncthreads); one LDS reduce
// + atomic round per block. Ring indices for tile t+512 prefetched while
// gathering tile t.
template<int WRITE_BF16>
__global__ __launch_bounds__(256) void k2_gather(
    const u32* __restrict__ Gt, const int* __restrict__ ring,
    const float* __restrict__ bias, u32* __restrict__ Y, float* __restrict__ outF,
    float* __restrict__ gsum, float* __restrict__ gsum2) {
  const int bid = blockIdx.x;
  const int b = (bid & 7) >> 1;                    // XCD bid%8 -> 2 XCDs per b
  const int sub = ((bid >> 3) << 1) | (bid & 1);   // 0..511 within b
  const int t = threadIdx.x;
  const int gid = t >> 3;    // face within 32-face tile
  const int cs = t & 7;      // 16 B channel slice (channels cs*8 .. cs*8+7)

  __shared__ float rs[32][68];
  __shared__ float rs2[32][68];

  float bv[8];
  #pragma unroll
  for (int i = 0; i < 8; i++) bv[i] = bias[cs * 8 + i];

  const u32* Gb = Gt + (size_t)b * Fn * 32;
  const int* rb = ring + (size_t)b * Fn * Kn;

  float sacc[8], s2acc[8];
  #pragma unroll
  for (int i = 0; i < 8; i++) { sacc[i] = 0.f; s2acc[i] = 0.f; }

  const int ntiles = (Fn + 31) / 32;   // 1563

  int tile = sub;
  i32x4 r0, r1, r2, r3;
  if (tile < ntiles) {
    int fa = tile * 32 + gid;
    int fc = fa < Fn ? fa : Fn - 1;    // clamp: last tile has 16 invalid faces
    const i32x4* rp = (const i32x4*)(rb + (size_t)fc * Kn);
    r0 = __builtin_nontemporal_load(&rp[0]);
    r1 = __builtin_nontemporal_load(&rp[1]);
    r2 = __builtin_nontemporal_load(&rp[2]);
    r3 = __builtin_nontemporal_load(&rp[3]);
  }

  for (; tile < ntiles; tile += 512) {
    const int fa = tile * 32 + gid;
    const bool valid = fa < Fn;
    int idx[16] = {r0[0],r0[1],r0[2],r0[3], r1[0],r1[1],r1[2],r1[3],
                   r2[0],r2[1],r2[2],r2[3], r3[0],r3[1],r3[2],r3[3]};

    // prefetch next tile's ring indices (hides ring latency under gathers)
    const int ntile = tile + 512;
    if (ntile < ntiles) {
      int nfa = ntile * 32 + gid;
      int nfc = nfa < Fn ? nfa : Fn - 1;
      const i32x4* rp = (const i32x4*)(rb + (size_t)nfc * Kn);
      r0 = __builtin_nontemporal_load(&rp[0]);
      r1 = __builtin_nontemporal_load(&rp[1]);
      r2 = __builtin_nontemporal_load(&rp[2]);
      r3 = __builtin_nontemporal_load(&rp[3]);
    }

    float acc[8];
    #pragma unroll
    for (int i = 0; i < 8; i++) acc[i] = 0.f;

    u32x4 v[8];
    #pragma unroll
    for (int k = 0; k < 8; k++)
      v[k] = *(const u32x4*)(Gb + (size_t)idx[k] * 32 + cs * 4);
    #pragma unroll
    for (int k = 0; k < 8; k++) {
      #pragma unroll
      for (int p = 0; p < 4; p++) {
        u32 uu = v[k][p];
        acc[2*p]   += __uint_as_float(uu << 16);
        acc[2*p+1] += __uint_as_float(uu & 0xffff0000u);
      }
    }
    #pragma unroll
    for (int k = 0; k < 8; k++)
      v[k] = *(const u32x4*)(Gb + (size_t)idx[8 + k] * 32 + cs * 4);
    #pragma unroll
    for (int k = 0; k < 8; k++) {
      #pragma unroll
      for (int p = 0; p < 4; p++) {
        u32 uu = v[k][p];
        acc[2*p]   += __uint_as_float(uu << 16);
        acc[2*p+1] += __uint_as_float(uu & 0xffff0000u);
      }
    }

    float yv[8];
    #pragma unroll
    for (int i = 0; i < 8; i++) yv[i] = acc[i] + bv[i];

    if (valid) {
      if (WRITE_BF16) {
        u32x4 pv;
        pv[0] = pack2(yv[0], yv[1]); pv[1] = pack2(yv[2], yv[3]);
        pv[2] = pack2(yv[4], yv[5]); pv[3] = pack2(yv[6], yv[7]);
        __builtin_nontemporal_store(pv,
            (u32x4*)(Y + ((size_t)b * Fn + fa) * 32 + cs * 4));
      } else {
        #pragma unroll
        for (int i = 0; i < 8; i++)
          outF[((size_t)b * 64 + cs * 8 + i) * Fn + fa] = yv[i];
      }
      #pragma unroll
      for (int i = 0; i < 8; i++) {
        sacc[i] += yv[i];
        s2acc[i] += yv[i] * yv[i];
      }
    }
  }

  // block-level stats reduce: rs[gid][ch], then 32-row column sums
  #pragma unroll
  for (int i = 0; i < 8; i++) {
    rs[gid][cs * 8 + i] = sacc[i];
    rs2[gid][cs * 8 + i] = s2acc[i];
  }
  __syncthreads();
  if (t < 64) {
    float s = 0.f;
    #pragma unroll
    for (int g = 0; g < 32; g++) s += rs[g][t];
    atomicAdd(&gsum[t], s);
  } else if (t < 128) {
    const int ch = t - 64;
    float s2 = 0.f;
    #pragma unroll
    for (int g = 0; g < 32; g++) s2 += rs2[g][ch];
    atomicAdd(&gsum2[ch], s2);
  }
}

__global__ void k3_stats(const float* __restrict__ gsum, const float* __restrict__ gsum2,
                         const float* __restrict__ gamma, const float* __restrict__ beta,
                         float* __restrict__ ab) {
  int o = threadIdx.x;
  if (o < 64) {
    float inv = 1.0f / (float)NTOT;
    float mean = gsum[o] * inv;
    float var = gsum2[o] * inv - mean * mean;  // biased
    float r = rsqrtf(var + EPS);
    float a = gamma[o] * r;
    ab[o] = a;
    ab[64 + o] = beta[o] - mean * a;
  }
}

// k4 (bf16, k3 fused): transpose Y[b][face][64ch] bf16 -> out[b][ch][face] fp32
// with BN affine + relu. 64-face x 64-ch tiles via LDS; coalesced both sides.
__global__ __launch_bounds__(256) void k4_norm_bf(
    const u32* __restrict__ Y, const float* __restrict__ gsum,
    const float* __restrict__ gsum2, const float* __restrict__ gamma,
    const float* __restrict__ beta, float* __restrict__ out) {
  const int b = blockIdx.y;
  const int f0 = blockIdx.x * 64;
  const int t = threadIdx.x;
  __shared__ u32 ys[32][65];   // [ch-pair][face], pad 65 -> ~2-way banks

  #pragma unroll
  for (int j = 0; j < 2; j++) {
    int o = j * 1024 + t * 4;        // u32 offset in 64x32 tile
    int fl = o >> 5, sl = o & 31;
    u32x4 vv = (u32x4)(0u);
    if (f0 + fl < Fn)
      vv = *(const u32x4*)(Y + ((size_t)b * Fn + f0 + fl) * 32 + sl);
    ys[sl + 0][fl] = vv[0]; ys[sl + 1][fl] = vv[1];
    ys[sl + 2][fl] = vv[2]; ys[sl + 3][fl] = vv[3];
  }
  __syncthreads();

  const float inv = 1.0f / (float)NTOT;
  const int fi = t & 15, g = t >> 4;
  const int fbase = 4 * fi;
  #pragma unroll
  for (int j = 0; j < 4; j++) {
    int ch = g * 4 + j;
    float mean = gsum[ch] * inv;
    float var = gsum2[ch] * inv - mean * mean;
    float a = gamma[ch] * rsqrtf(var + EPS);
    float cc = beta[ch] - mean * a;
    if (f0 + fbase < Fn) {           // Fn%4==0 -> whole float4 valid
      const int c2 = ch >> 1;
      const bool hi = ch & 1;
      float r[4];
      #pragma unroll
      for (int rr = 0; rr < 4; rr++) {
        u32 u = ys[c2][fbase + rr];
        float xv = __uint_as_float(hi ? (u & 0xffff0000u) : (u << 16));
        r[rr] = fmaxf(fmaf(xv, a, cc), 0.f);
      }
      float4 res = make_float4(r[0], r[1], r[2], r[3]);
      *(float4*)(out + ((size_t)b * 64 + ch) * Fn + f0 + fbase) = res;
    }
  }
}

// k4 (fallback): in-place fp32 normalize
__global__ __launch_bounds__(256) void k4_norm_f32(float* __restrict__ out,
                                                   const float* __restrict__ ab) {
  int i = blockIdx.x * 256 + threadIdx.x;   // float4 index
  int o = (i / (Fn / 4)) & 63;
  float a = ab[o], c = ab[64 + o];
  float4 v = ((float4*)out)[i];
  v.x = fmaxf(fmaf(v.x, a, c), 0.f);
  v.y = fmaxf(fmaf(v.y, a, c), 0.f);
  v.z = fmaxf(fmaf(v.z, a, c), 0.f);
  v.w = fmaxf(fmaf(v.w, a, c), 0.f);
  ((float4*)out)[i] = v;
}

extern "C" void kernel_launch(void* const* d_in, const int* in_sizes, int n_in,
                              void* d_out, int out_size, void* d_ws, size_t ws_size,
                              hipStream_t stream) {
  const float* fea   = (const float*)d_in[0];
  const int*   ring  = (const int*)d_in[1];
  const float* W     = (const float*)d_in[2];
  const float* bias  = (const float*)d_in[3];
  const float* gamma = (const float*)d_in[4];
  const float* beta  = (const float*)d_in[5];
  float* out = (float*)d_out;

  u32* Gt = (u32*)d_ws;                                   // [B][Fn][32 u32] = 25.6 MB
  const size_t gtBytes = (size_t)Bn * Fn * 32 * 4;
  const size_t yBytes  = (size_t)Bn * Fn * 32 * 4;        // [B][Fn][32 u32] = 25.6 MB
  const bool bf16y = ws_size >= gtBytes + yBytes + 1024;

  u32* Y = Gt + (size_t)Bn * Fn * 32;
  float* gsum  = bf16y ? (float*)((char*)d_ws + gtBytes + yBytes)
                       : (float*)((char*)d_ws + gtBytes);
  float* gsum2 = gsum + 64;
  float* ab    = gsum + 128;

  hipMemsetAsync(gsum, 0, 2 * 64 * sizeof(float), stream);
  k1_mfma<<<dim3((Fn + 127) / 128, Bn), 256, 0, stream>>>(fea, W, Gt);
  if (bf16y) {
    k2_gather<1><<<dim3(2048), 256, 0, stream>>>(Gt, ring, bias, Y, out, gsum, gsum2);
    k4_norm_bf<<<dim3((Fn + 63) / 64, Bn), 256, 0, stream>>>(Y, gsum, gsum2, gamma, beta, out);
  } else {
    k2_gather<0><<<dim3(2048), 256, 0, stream>>>(Gt, ring, bias, Y, out, gsum, gsum2);
    k3_stats<<<1, 64, 0, stream>>>(gsum, gsum2, gamma, beta, ab);
    k4_norm_f32<<<dim3((Bn * Cn * Fn / 4) / 256), 256, 0, stream>>>(out, ab);
  }
}